// Round 1
// baseline (775.860 us; speedup 1.0000x reference)
//
#include <hip/hip_runtime.h>

#define B_ 8
#define C_ 2048
#define DIM_ 512
#define H_ 512
#define N_ (B_*C_)
#define NEG_SLOPE 0.01f

// workspace layout (float offsets)
#define WS_WCOMB   0          // 512*512
#define WS_BCOMB   262144     // 512
#define WS_WQ      262656     // 512
#define WS_WK      263168     // 512
#define WS_CQB     263680     // 1  (cq + b_score)
#define WS_CK      263681     // 1
#define WS_SQP     263684     // 16384  sq + cq + b_score
#define WS_SKP     280068     // 16384  sk + ck
#define WS_RMAX    296452     // 16384
#define WS_RSUM    312836     // 16384
#define WS_U       329220     // 16384*512   u = F @ (W_v@W_out) + b_v@W_out

// ---------------- prep: wq_vec[e] = sum_h W_w[e,h]*a[h]; wk_vec[e] = sum_h W_w[e,512+h]*a[512+h]
__global__ void k_prep_wqk(const float* __restrict__ W_w, const float* __restrict__ a_score, float* ws) {
    int wave = threadIdx.x >> 6, lane = threadIdx.x & 63;
    int e = blockIdx.x * 4 + wave;
    const float4* R4 = (const float4*)(W_w + (size_t)e * 1536);
    const float4* A4 = (const float4*)a_score;
    float aq = 0.f, ak = 0.f;
#pragma unroll
    for (int k = 0; k < 2; ++k) {
        float4 f = R4[lane + 64 * k];
        float4 a = A4[lane + 64 * k];
        aq += f.x * a.x + f.y * a.y + f.z * a.z + f.w * a.w;
        float4 g = R4[128 + lane + 64 * k];
        float4 a2 = A4[128 + lane + 64 * k];
        ak += g.x * a2.x + g.y * a2.y + g.z * a2.z + g.w * a2.w;
    }
#pragma unroll
    for (int off = 32; off; off >>= 1) { aq += __shfl_xor(aq, off); ak += __shfl_xor(ak, off); }
    if (lane == 0) { ws[WS_WQ + e] = aq; ws[WS_WK + e] = ak; }
}

// cqb = b_q . a[:H] + b_score ; ck = b_k . a[H:]
__global__ void k_prep_cqk(const float* __restrict__ b_w, const float* __restrict__ a_score,
                           const float* __restrict__ b_score, float* ws) {
    __shared__ float s1[512], s2[512];
    int t = threadIdx.x;
    s1[t] = b_w[t] * a_score[t];
    s2[t] = b_w[512 + t] * a_score[512 + t];
    __syncthreads();
    for (int off = 256; off > 0; off >>= 1) {
        if (t < off) { s1[t] += s1[t + off]; s2[t] += s2[t + off]; }
        __syncthreads();
    }
    if (t == 0) { ws[WS_CQB] = s1[0] + b_score[0]; ws[WS_CK] = s2[0]; }
}

// W_comb[e,d] = sum_h W_w[e, 1024+h] * W_out[h,d]
__global__ __launch_bounds__(256) void k_wcomb(const float* __restrict__ W_w,
                                               const float* __restrict__ W_out, float* ws) {
    int d = blockIdx.x * 256 + threadIdx.x;
    int e_base = blockIdx.y * 16;
    float acc[16] = {};
    for (int h = 0; h < 512; ++h) {
        float wo = W_out[h * 512 + d];
#pragma unroll
        for (int e0 = 0; e0 < 16; ++e0)
            acc[e0] = fmaf(W_w[(size_t)(e_base + e0) * 1536 + 1024 + h], wo, acc[e0]);
    }
#pragma unroll
    for (int e0 = 0; e0 < 16; ++e0)
        ws[WS_WCOMB + (size_t)(e_base + e0) * 512 + d] = acc[e0];
}

// b_comb[d] = sum_h b_w[1024+h] * W_out[h,d]
__global__ void k_bcomb(const float* __restrict__ b_w, const float* __restrict__ W_out, float* ws) {
    int d = blockIdx.x * 256 + threadIdx.x;
    float acc = 0.f;
    for (int h = 0; h < 512; ++h) acc = fmaf(b_w[1024 + h], W_out[h * 512 + d], acc);
    ws[WS_BCOMB + d] = acc;
}

// sq'[n] = F[n,:].wq + cqb ; sk'[n] = F[n,:].wk + ck    (one wave per row)
__global__ void k_sqsk(const float* __restrict__ feat, float* ws) {
    int wave = threadIdx.x >> 6, lane = threadIdx.x & 63;
    int n = blockIdx.x * 4 + wave;
    const float4* F4 = (const float4*)(feat + (size_t)n * 512);
    const float4* WQ4 = (const float4*)(ws + WS_WQ);
    const float4* WK4 = (const float4*)(ws + WS_WK);
    float aq = 0.f, ak = 0.f;
#pragma unroll
    for (int k = 0; k < 2; ++k) {
        float4 f = F4[lane + 64 * k];
        float4 q = WQ4[lane + 64 * k];
        float4 kk = WK4[lane + 64 * k];
        aq += f.x * q.x + f.y * q.y + f.z * q.z + f.w * q.w;
        ak += f.x * kk.x + f.y * kk.y + f.z * kk.z + f.w * kk.w;
    }
#pragma unroll
    for (int off = 32; off; off >>= 1) { aq += __shfl_xor(aq, off); ak += __shfl_xor(ak, off); }
    if (lane == 0) {
        ws[WS_SQP + n] = aq + ws[WS_CQB];
        ws[WS_SKP + n] = ak + ws[WS_CK];
    }
}

// u = F @ W_comb + b_comb   (fp32 tiled GEMM 64x64, BK=16, 256 thr, 4x4/thread)
__global__ __launch_bounds__(256) void k_ugemm(const float* __restrict__ A, float* ws) {
    __shared__ float As[16][64];
    __shared__ float Bs[16][64];
    int t = threadIdx.x;
    int m0 = blockIdx.y * 64, n0 = blockIdx.x * 64;
    int ty = t >> 4, tx = t & 15;
    float acc[4][4] = {};
    const float* Bp = ws + WS_WCOMB;
    for (int k0 = 0; k0 < 512; k0 += 16) {
        int row = t >> 2, kq = t & 3;
        float4 a4 = *(const float4*)(A + (size_t)(m0 + row) * 512 + k0 + kq * 4);
        As[kq * 4 + 0][row] = a4.x; As[kq * 4 + 1][row] = a4.y;
        As[kq * 4 + 2][row] = a4.z; As[kq * 4 + 3][row] = a4.w;
        int kr = t >> 4, c4 = t & 15;
        *(float4*)&Bs[kr][c4 * 4] = *(const float4*)(Bp + (size_t)(k0 + kr) * 512 + n0 + c4 * 4);
        __syncthreads();
#pragma unroll
        for (int kk = 0; kk < 16; ++kk) {
            float ra[4], rb[4];
#pragma unroll
            for (int i = 0; i < 4; ++i) ra[i] = As[kk][ty * 4 + i];
#pragma unroll
            for (int j = 0; j < 4; ++j) rb[j] = Bs[kk][tx * 4 + j];
#pragma unroll
            for (int i = 0; i < 4; ++i)
#pragma unroll
                for (int j = 0; j < 4; ++j) acc[i][j] = fmaf(ra[i], rb[j], acc[i][j]);
        }
        __syncthreads();
    }
    float4 bb = *(const float4*)(ws + WS_BCOMB + n0 + tx * 4);
#pragma unroll
    for (int i = 0; i < 4; ++i) {
        float4 o;
        o.x = acc[i][0] + bb.x; o.y = acc[i][1] + bb.y;
        o.z = acc[i][2] + bb.z; o.w = acc[i][3] + bb.w;
        *(float4*)(ws + WS_U + (size_t)(m0 + ty * 4 + i) * 512 + n0 + tx * 4) = o;
    }
}

// pass A: per row, m = max_j z, s = sum_j exp(z-m),  z = mask*lrelu(sq'+sk')
__global__ void k_rowstats(const float* __restrict__ mask, float* ws) {
    int wave = threadIdx.x >> 6, lane = threadIdx.x & 63;
    int n = blockIdx.x * 4 + wave;
    int b = n >> 11, i = n & 2047;
    const float4* M4 = (const float4*)(mask + ((size_t)b * C_ + i) * C_);
    const float4* SK4 = (const float4*)(ws + WS_SKP + (size_t)b * C_);
    const float sq = ws[WS_SQP + n];
    float z[32];
    float m = -1e30f;
#pragma unroll
    for (int k = 0; k < 8; ++k) {
        float4 mk = M4[k * 64 + lane];
        float4 sk = SK4[k * 64 + lane];
        float t0;
        t0 = sq + sk.x; t0 = (t0 >= 0.f ? t0 : t0 * NEG_SLOPE) * mk.x; z[k * 4 + 0] = t0;
        t0 = sq + sk.y; t0 = (t0 >= 0.f ? t0 : t0 * NEG_SLOPE) * mk.y; z[k * 4 + 1] = t0;
        t0 = sq + sk.z; t0 = (t0 >= 0.f ? t0 : t0 * NEG_SLOPE) * mk.z; z[k * 4 + 2] = t0;
        t0 = sq + sk.w; t0 = (t0 >= 0.f ? t0 : t0 * NEG_SLOPE) * mk.w; z[k * 4 + 3] = t0;
    }
#pragma unroll
    for (int q = 0; q < 32; ++q) m = fmaxf(m, z[q]);
#pragma unroll
    for (int off = 32; off; off >>= 1) m = fmaxf(m, __shfl_xor(m, off));
    float s = 0.f;
#pragma unroll
    for (int q = 0; q < 32; ++q) s += __expf(z[q] - m);
#pragma unroll
    for (int off = 32; off; off >>= 1) s += __shfl_xor(s, off);
    if (lane == 0) { ws[WS_RMAX + n] = m; ws[WS_RSUM + n] = s; }
}

// pass B: out[b,i,d] = sum_j p_ij * u[b,j,d] + b_out[d]
// block: one batch b, 32 i-rows, full 512 d. thread owns 2 d-columns.
__global__ __launch_bounds__(256) void k_attnout(const float* __restrict__ mask,
                                                 const float* __restrict__ b_out,
                                                 const float* ws, float* __restrict__ out) {
    const int t = threadIdx.x;
    const int bid = blockIdx.x;
    const int b = bid & 7;          // batch -> XCD affinity (u[b] stays in one L2)
    const int i0 = (bid >> 3) * 32;
    __shared__ float Ps[32][32];
    __shared__ float sqs[32], ms[32], rinv[32];
    if (t < 32) {
        int n = b * C_ + i0 + t;
        sqs[t] = ws[WS_SQP + n];
        ms[t] = ws[WS_RMAX + n];
        rinv[t] = 1.0f / ws[WS_RSUM + n];
    }
    __syncthreads();
    const int d0 = t * 2;
    float2 acc[32];
#pragma unroll
    for (int i = 0; i < 32; ++i) { acc[i].x = 0.f; acc[i].y = 0.f; }
    const int i_p = t >> 3, j4 = t & 7;
    const float* mrow = mask + (size_t)b * C_ * C_ + (size_t)(i0 + i_p) * C_;
    const float* skb = ws + WS_SKP + (size_t)b * C_;
    const float* up = ws + WS_U + (size_t)b * C_ * DIM_;
    const float sqv = sqs[i_p], mv = ms[i_p], riv = rinv[i_p];
    for (int jt = 0; jt < C_; jt += 32) {
        const int j = jt + j4 * 4;
        float4 mk = *(const float4*)(mrow + j);
        float4 sk = *(const float4*)(skb + j);
        float4 p;
        {
            float z;
            z = sqv + sk.x; z = (z >= 0.f ? z : z * NEG_SLOPE) * mk.x; p.x = __expf(z - mv) * riv;
            z = sqv + sk.y; z = (z >= 0.f ? z : z * NEG_SLOPE) * mk.y; p.y = __expf(z - mv) * riv;
            z = sqv + sk.z; z = (z >= 0.f ? z : z * NEG_SLOPE) * mk.z; p.z = __expf(z - mv) * riv;
            z = sqv + sk.w; z = (z >= 0.f ? z : z * NEG_SLOPE) * mk.w; p.w = __expf(z - mv) * riv;
        }
        __syncthreads();                 // previous tile's Ps reads done
        *(float4*)&Ps[i_p][j4 * 4] = p;
        __syncthreads();
        float2 u2[32];
#pragma unroll
        for (int jj = 0; jj < 32; ++jj)
            u2[jj] = *(const float2*)(up + (size_t)(jt + jj) * DIM_ + d0);
#pragma unroll
        for (int i = 0; i < 32; ++i) {
#pragma unroll
            for (int jq = 0; jq < 8; ++jq) {
                float4 pv = *(const float4*)&Ps[i][jq * 4];   // uniform addr -> broadcast
                acc[i].x = fmaf(pv.x, u2[jq * 4 + 0].x, acc[i].x);
                acc[i].y = fmaf(pv.x, u2[jq * 4 + 0].y, acc[i].y);
                acc[i].x = fmaf(pv.y, u2[jq * 4 + 1].x, acc[i].x);
                acc[i].y = fmaf(pv.y, u2[jq * 4 + 1].y, acc[i].y);
                acc[i].x = fmaf(pv.z, u2[jq * 4 + 2].x, acc[i].x);
                acc[i].y = fmaf(pv.z, u2[jq * 4 + 2].y, acc[i].y);
                acc[i].x = fmaf(pv.w, u2[jq * 4 + 3].x, acc[i].x);
                acc[i].y = fmaf(pv.w, u2[jq * 4 + 3].y, acc[i].y);
            }
        }
    }
    float2 bo = *(const float2*)(b_out + d0);
    float* orow = out + ((size_t)(b * C_) + i0) * DIM_;
#pragma unroll
    for (int i = 0; i < 32; ++i) {
        float2 o;
        o.x = acc[i].x + bo.x;
        o.y = acc[i].y + bo.y;
        *(float2*)(orow + (size_t)i * DIM_ + d0) = o;
    }
}

extern "C" void kernel_launch(void* const* d_in, const int* in_sizes, int n_in,
                              void* d_out, int out_size, void* d_ws, size_t ws_size,
                              hipStream_t stream) {
    const float* features = (const float*)d_in[0];
    const float* mask     = (const float*)d_in[1];
    const float* W_w      = (const float*)d_in[2];
    const float* b_w      = (const float*)d_in[3];
    const float* a_score  = (const float*)d_in[4];
    const float* b_score  = (const float*)d_in[5];
    const float* W_out    = (const float*)d_in[6];
    const float* b_out    = (const float*)d_in[7];
    float* out = (float*)d_out;
    float* ws  = (float*)d_ws;

    k_prep_wqk<<<128, 256, 0, stream>>>(W_w, a_score, ws);
    k_prep_cqk<<<1, 512, 0, stream>>>(b_w, a_score, b_score, ws);
    k_wcomb<<<dim3(2, 32), 256, 0, stream>>>(W_w, W_out, ws);
    k_bcomb<<<2, 256, 0, stream>>>(b_w, W_out, ws);
    k_sqsk<<<4096, 256, 0, stream>>>(features, ws);
    k_ugemm<<<dim3(8, 256), 256, 0, stream>>>(features, ws);
    k_rowstats<<<4096, 256, 0, stream>>>(mask, ws);
    k_attnout<<<512, 256, 0, stream>>>(mask, b_out, ws, out);
}

// Round 2
// 266.066 us; speedup vs baseline: 2.9160x; 2.9160x over previous
//
#include <hip/hip_runtime.h>
#include <hip/hip_bf16.h>

#define B_ 8
#define C_ 2048
#define DIM_ 512
#define NEG_SLOPE 0.01f

typedef short bf16x8 __attribute__((ext_vector_type(8)));
typedef float f32x4 __attribute__((ext_vector_type(4)));

// ---- workspace byte offsets
#define WT_OFF   0                        // bf16 Wt[512][512] (W_comb^T)
#define UT_OFF   524288                   // bf16 Ut[8*512][2048]  (U^T per batch)
#define FP_OFF   (524288 + 16777216)      // fp32 region
// ---- float offsets inside fp32 region
#define BCOMB_F  0
#define WQ_F     512
#define WK_F     1024
#define CQB_F    1536
#define CK_F     1537
#define SQP_F    2048
#define SKP_F    18432
#define RMAX_F   34816
#define RSUM_F   51200

static __device__ __forceinline__ unsigned short bf16u(float x) {
    union { __hip_bfloat16 h; unsigned short u; } c;
    c.h = __float2bfloat16(x);
    return c.u;
}

// wq_vec[e] = sum_h W_w[e,h]*a[h]; wk_vec[e] = sum_h W_w[e,512+h]*a[512+h]
__global__ void k_prep_wqk(const float* __restrict__ W_w, const float* __restrict__ a_score, float* wsf) {
    int wave = threadIdx.x >> 6, lane = threadIdx.x & 63;
    int e = blockIdx.x * 4 + wave;
    const float4* R4 = (const float4*)(W_w + (size_t)e * 1536);
    const float4* A4 = (const float4*)a_score;
    float aq = 0.f, ak = 0.f;
#pragma unroll
    for (int k = 0; k < 2; ++k) {
        float4 f = R4[lane + 64 * k];
        float4 a = A4[lane + 64 * k];
        aq += f.x * a.x + f.y * a.y + f.z * a.z + f.w * a.w;
        float4 g = R4[128 + lane + 64 * k];
        float4 a2 = A4[128 + lane + 64 * k];
        ak += g.x * a2.x + g.y * a2.y + g.z * a2.z + g.w * a2.w;
    }
#pragma unroll
    for (int off = 32; off; off >>= 1) { aq += __shfl_xor(aq, off); ak += __shfl_xor(ak, off); }
    if (lane == 0) { wsf[WQ_F + e] = aq; wsf[WK_F + e] = ak; }
}

__global__ void k_prep_cqk(const float* __restrict__ b_w, const float* __restrict__ a_score,
                           const float* __restrict__ b_score, float* wsf) {
    __shared__ float s1[512], s2[512];
    int t = threadIdx.x;
    s1[t] = b_w[t] * a_score[t];
    s2[t] = b_w[512 + t] * a_score[512 + t];
    __syncthreads();
    for (int off = 256; off > 0; off >>= 1) {
        if (t < off) { s1[t] += s1[t + off]; s2[t] += s2[t + off]; }
        __syncthreads();
    }
    if (t == 0) { wsf[CQB_F] = s1[0] + b_score[0]; wsf[CK_F] = s2[0]; }
}

// Wt[d][e] = sum_h W_w[e,1024+h] * W_out[h,d]   (bf16, transposed W_comb)
__global__ __launch_bounds__(256) void k_wt(const float* __restrict__ W_w,
                                            const float* __restrict__ W_out, char* wsb) {
    int d = blockIdx.x * 256 + threadIdx.x;
    int e_base = blockIdx.y * 16;
    float acc[16] = {};
    for (int h = 0; h < 512; ++h) {
        float wo = W_out[h * 512 + d];
#pragma unroll
        for (int e0 = 0; e0 < 16; ++e0)
            acc[e0] = fmaf(W_w[(size_t)(e_base + e0) * 1536 + 1024 + h], wo, acc[e0]);
    }
    unsigned short* Wt = (unsigned short*)(wsb + WT_OFF);
#pragma unroll
    for (int e0 = 0; e0 < 16; ++e0)
        Wt[(size_t)d * 512 + e_base + e0] = bf16u(acc[e0]);
}

// b_comb[d] = sum_h b_w[1024+h] * W_out[h,d]
__global__ void k_bcomb(const float* __restrict__ b_w, const float* __restrict__ W_out, float* wsf) {
    int d = blockIdx.x * 256 + threadIdx.x;
    float acc = 0.f;
    for (int h = 0; h < 512; ++h) acc = fmaf(b_w[1024 + h], W_out[h * 512 + d], acc);
    wsf[BCOMB_F + d] = acc;
}

// sq'[n], sk'[n]
__global__ void k_sqsk(const float* __restrict__ feat, float* wsf) {
    int wave = threadIdx.x >> 6, lane = threadIdx.x & 63;
    int n = blockIdx.x * 4 + wave;
    const float4* F4 = (const float4*)(feat + (size_t)n * 512);
    const float4* WQ4 = (const float4*)(wsf + WQ_F);
    const float4* WK4 = (const float4*)(wsf + WK_F);
    float aq = 0.f, ak = 0.f;
#pragma unroll
    for (int k = 0; k < 2; ++k) {
        float4 f = F4[lane + 64 * k];
        float4 q = WQ4[lane + 64 * k];
        float4 kk = WK4[lane + 64 * k];
        aq += f.x * q.x + f.y * q.y + f.z * q.z + f.w * q.w;
        ak += f.x * kk.x + f.y * kk.y + f.z * kk.z + f.w * kk.w;
    }
#pragma unroll
    for (int off = 32; off; off >>= 1) { aq += __shfl_xor(aq, off); ak += __shfl_xor(ak, off); }
    if (lane == 0) {
        wsf[SQP_F + n] = aq + wsf[CQB_F];
        wsf[SKP_F + n] = ak + wsf[CK_F];
    }
}

// per-row max & sum of z = mask * lrelu(sq'+sk')
__global__ void k_rowstats(const float* __restrict__ mask, float* wsf) {
    int wave = threadIdx.x >> 6, lane = threadIdx.x & 63;
    int n = blockIdx.x * 4 + wave;
    int b = n >> 11, i = n & 2047;
    const float4* M4 = (const float4*)(mask + ((size_t)b * C_ + i) * C_);
    const float4* SK4 = (const float4*)(wsf + SKP_F + (size_t)b * C_);
    const float sq = wsf[SQP_F + n];
    float z[32];
    float m = -1e30f;
#pragma unroll
    for (int k = 0; k < 8; ++k) {
        float4 mk = M4[k * 64 + lane];
        float4 sk = SK4[k * 64 + lane];
        float t0;
        t0 = sq + sk.x; t0 = fmaxf(t0, t0 * NEG_SLOPE) * mk.x; z[k * 4 + 0] = t0;
        t0 = sq + sk.y; t0 = fmaxf(t0, t0 * NEG_SLOPE) * mk.y; z[k * 4 + 1] = t0;
        t0 = sq + sk.z; t0 = fmaxf(t0, t0 * NEG_SLOPE) * mk.z; z[k * 4 + 2] = t0;
        t0 = sq + sk.w; t0 = fmaxf(t0, t0 * NEG_SLOPE) * mk.w; z[k * 4 + 3] = t0;
    }
#pragma unroll
    for (int q = 0; q < 32; ++q) m = fmaxf(m, z[q]);
#pragma unroll
    for (int off = 32; off; off >>= 1) m = fmaxf(m, __shfl_xor(m, off));
    float s = 0.f;
#pragma unroll
    for (int q = 0; q < 32; ++q) s += __expf(z[q] - m);
#pragma unroll
    for (int off = 32; off; off >>= 1) s += __shfl_xor(s, off);
    if (lane == 0) { wsf[RMAX_F + n] = m; wsf[RSUM_F + n] = s; }
}

// Ut[b,d,j] = sum_e Wt[d,e] * F[b,j,e]   (bf16 MFMA; full K=512 staged in LDS)
__global__ __launch_bounds__(512) void k_ut(const float* __restrict__ F, char* __restrict__ wsb) {
    __shared__ unsigned short Fb[64][520];   // [j][e] +8 pad
    const int t = threadIdx.x;
    const int bid = blockIdx.x;
    const int b = bid & 7, j0 = (bid >> 3) * 64;
    const unsigned short* Wt = (const unsigned short*)(wsb + WT_OFF);
    unsigned short* Ut = (unsigned short*)(wsb + UT_OFF) + (size_t)b * 512 * 2048;
    const float* Ft = F + ((size_t)(b * C_ + j0)) * 512;   // 64x512 tile, contiguous
#pragma unroll
    for (int q = 0; q < 16; ++q) {
        float4 v = *(const float4*)(Ft + (size_t)q * 2048 + t * 4);
        int jr = 4 * q + (t >> 7);
        int e = (t & 127) * 4;
        unsigned int lo = (unsigned int)bf16u(v.x) | ((unsigned int)bf16u(v.y) << 16);
        unsigned int hi = (unsigned int)bf16u(v.z) | ((unsigned int)bf16u(v.w) << 16);
        *(uint2*)&Fb[jr][e] = make_uint2(lo, hi);
    }
    __syncthreads();
    const int l = t & 63, lr = l & 15, lg = l >> 4;
    const int d0 = (t >> 6) * 64;
    f32x4 acc[4][4];
#pragma unroll
    for (int m = 0; m < 4; ++m)
#pragma unroll
        for (int n = 0; n < 4; ++n) acc[m][n] = (f32x4){0.f, 0.f, 0.f, 0.f};
#pragma unroll
    for (int ks = 0; ks < 16; ++ks) {
        bf16x8 af[4], bv[4];
#pragma unroll
        for (int m = 0; m < 4; ++m)
            af[m] = *(const bf16x8*)(Wt + (size_t)(d0 + 16 * m + lr) * 512 + ks * 32 + 8 * lg);
#pragma unroll
        for (int n = 0; n < 4; ++n)
            bv[n] = *(const bf16x8*)&Fb[16 * n + lr][ks * 32 + 8 * lg];
#pragma unroll
        for (int m = 0; m < 4; ++m)
#pragma unroll
            for (int n = 0; n < 4; ++n)
                acc[m][n] = __builtin_amdgcn_mfma_f32_16x16x32_bf16(af[m], bv[n], acc[m][n], 0, 0, 0);
    }
#pragma unroll
    for (int m = 0; m < 4; ++m)
#pragma unroll
        for (int n = 0; n < 4; ++n)
#pragma unroll
            for (int r = 0; r < 4; ++r) {
                int d = d0 + 16 * m + lg * 4 + r;
                int j = j0 + 16 * n + lr;
                Ut[(size_t)d * 2048 + j] = bf16u(acc[m][n][r]);
            }
}

// out[b,i,d] = rinv_i * sum_j exp(z_ij - m_i) * Ut[d,j]  + b_comb[d] + b_out[d]
__global__ __launch_bounds__(512) void k_attn(const float* __restrict__ mask,
                                              const float* __restrict__ b_out,
                                              char* __restrict__ wsb,
                                              float* __restrict__ out) {
    __shared__ unsigned short P[2][64][72];   // double-buffered P tile, +8 pad
    __shared__ float sqs[64], ms[64], rinv[64], bcbo[512];
    const int t = threadIdx.x;
    const int bid = blockIdx.x;
    const int b = bid & 7, i0 = (bid >> 3) * 64;
    const float* wsf = (const float*)(wsb + FP_OFF);
    const unsigned short* Ut = (const unsigned short*)(wsb + UT_OFF) + (size_t)b * 512 * 2048;
    if (t < 64) {
        int n = b * C_ + i0 + t;
        sqs[t] = wsf[SQP_F + n];
        ms[t] = wsf[RMAX_F + n];
        rinv[t] = 1.0f / wsf[RSUM_F + n];
    }
    bcbo[t] = wsf[BCOMB_F + t] + b_out[t];
    __syncthreads();
    const int ip = t >> 3, jc = t & 7;           // P-compute: row ip, 8 cols at jc*8
    const int l = t & 63, lr = l & 15, lg = l >> 4;
    const int dw = (t >> 6) * 64;                // wave's 64-col slice of d
    const float* mrow = mask + ((size_t)(b * C_ + i0 + ip)) * C_;
    const float* skb = wsf + SKP_F + b * C_;
    const float sqv = sqs[ip], mv = ms[ip];
    f32x4 acc[4][4];
#pragma unroll
    for (int m = 0; m < 4; ++m)
#pragma unroll
        for (int n = 0; n < 4; ++n) acc[m][n] = (f32x4){0.f, 0.f, 0.f, 0.f};

    auto computeP = [&](int kt, int buf) {
        const int j = kt * 64 + jc * 8;
        float4 mk0 = *(const float4*)(mrow + j);
        float4 mk1 = *(const float4*)(mrow + j + 4);
        float4 sk0 = *(const float4*)(skb + j);
        float4 sk1 = *(const float4*)(skb + j + 4);
        bf16x8 v;
        float z;
        z = sqv + sk0.x; z = fmaxf(z, z * NEG_SLOPE) * mk0.x; v[0] = (short)bf16u(__expf(z - mv));
        z = sqv + sk0.y; z = fmaxf(z, z * NEG_SLOPE) * mk0.y; v[1] = (short)bf16u(__expf(z - mv));
        z = sqv + sk0.z; z = fmaxf(z, z * NEG_SLOPE) * mk0.z; v[2] = (short)bf16u(__expf(z - mv));
        z = sqv + sk0.w; z = fmaxf(z, z * NEG_SLOPE) * mk0.w; v[3] = (short)bf16u(__expf(z - mv));
        z = sqv + sk1.x; z = fmaxf(z, z * NEG_SLOPE) * mk1.x; v[4] = (short)bf16u(__expf(z - mv));
        z = sqv + sk1.y; z = fmaxf(z, z * NEG_SLOPE) * mk1.y; v[5] = (short)bf16u(__expf(z - mv));
        z = sqv + sk1.z; z = fmaxf(z, z * NEG_SLOPE) * mk1.z; v[6] = (short)bf16u(__expf(z - mv));
        z = sqv + sk1.w; z = fmaxf(z, z * NEG_SLOPE) * mk1.w; v[7] = (short)bf16u(__expf(z - mv));
        *(bf16x8*)&P[buf][ip][jc * 8] = v;
    };

    computeP(0, 0);
    __syncthreads();
    for (int kt = 0; kt < 32; ++kt) {
        const int cur = kt & 1;
        if (kt + 1 < 32) computeP(kt + 1, cur ^ 1);
#pragma unroll
        for (int ks = 0; ks < 2; ++ks) {
            bf16x8 af[4], bv[4];
#pragma unroll
            for (int m = 0; m < 4; ++m)
                af[m] = *(const bf16x8*)&P[cur][16 * m + lr][ks * 32 + 8 * lg];
#pragma unroll
            for (int n = 0; n < 4; ++n)
                bv[n] = *(const bf16x8*)(Ut + (size_t)(dw + 16 * n + lr) * 2048 + kt * 64 + ks * 32 + 8 * lg);
#pragma unroll
            for (int m = 0; m < 4; ++m)
#pragma unroll
                for (int n = 0; n < 4; ++n)
                    acc[m][n] = __builtin_amdgcn_mfma_f32_16x16x32_bf16(af[m], bv[n], acc[m][n], 0, 0, 0);
        }
        __syncthreads();
    }
#pragma unroll
    for (int m = 0; m < 4; ++m) {
#pragma unroll
        for (int r = 0; r < 4; ++r) {
            const int irow = 16 * m + lg * 4 + r;
            const float rv = rinv[irow];
            float* orow = out + ((size_t)(b * C_ + i0 + irow)) * DIM_ + dw;
#pragma unroll
            for (int n = 0; n < 4; ++n)
                orow[16 * n + lr] = acc[m][n][r] * rv + bcbo[dw + 16 * n + lr];
        }
    }
}

extern "C" void kernel_launch(void* const* d_in, const int* in_sizes, int n_in,
                              void* d_out, int out_size, void* d_ws, size_t ws_size,
                              hipStream_t stream) {
    const float* features = (const float*)d_in[0];
    const float* mask     = (const float*)d_in[1];
    const float* W_w      = (const float*)d_in[2];
    const float* b_w      = (const float*)d_in[3];
    const float* a_score  = (const float*)d_in[4];
    const float* b_score  = (const float*)d_in[5];
    const float* W_out    = (const float*)d_in[6];
    const float* b_out    = (const float*)d_in[7];
    float* out = (float*)d_out;
    char* wsb  = (char*)d_ws;
    float* wsf = (float*)(wsb + FP_OFF);

    k_prep_wqk<<<128, 256, 0, stream>>>(W_w, a_score, wsf);
    k_prep_cqk<<<1, 512, 0, stream>>>(b_w, a_score, b_score, wsf);
    k_wt<<<dim3(2, 32), 256, 0, stream>>>(W_w, W_out, wsb);
    k_bcomb<<<2, 256, 0, stream>>>(b_w, W_out, wsf);
    k_sqsk<<<4096, 256, 0, stream>>>(features, wsf);
    k_rowstats<<<4096, 256, 0, stream>>>(mask, wsf);
    k_ut<<<256, 512, 0, stream>>>(features, wsb);
    k_attn<<<256, 512, 0, stream>>>(mask, b_out, wsb, out);
}

// Round 3
// 177.658 us; speedup vs baseline: 4.3672x; 1.4976x over previous
//
#include <hip/hip_runtime.h>
#include <hip/hip_bf16.h>

#define B_ 8
#define C_ 2048
#define DIM_ 512
#define NEG_SLOPE 0.01f

typedef short bf16x8 __attribute__((ext_vector_type(8)));
typedef float f32x4 __attribute__((ext_vector_type(4)));

// ---- workspace byte offsets
#define WT_OFF   0                        // bf16 Wt[512][512] (W_comb^T)
#define UT_OFF   524288                   // bf16 Ut[8*512][2048]  (U^T per batch)
#define FP_OFF   (524288 + 16777216)      // fp32 region
// ---- float offsets inside fp32 region
#define BCOMB_F  0
#define WQ_F     512
#define WK_F     1024
#define CQB_F    1536
#define CK_F     1537
#define SQP_F    2048
#define SKP_F    18432
#define RMAX_F   34816
#define RSUM_F   51200

static __device__ __forceinline__ unsigned short bf16u(float x) {
    union { __hip_bfloat16 h; unsigned short u; } c;
    c.h = __float2bfloat16(x);
    return c.u;
}

// wq_vec[e] = sum_h W_w[e,h]*a[h]; wk_vec[e] = sum_h W_w[e,512+h]*a[512+h]
__global__ void k_prep_wqk(const float* __restrict__ W_w, const float* __restrict__ a_score, float* wsf) {
    int wave = threadIdx.x >> 6, lane = threadIdx.x & 63;
    int e = blockIdx.x * 4 + wave;
    const float4* R4 = (const float4*)(W_w + (size_t)e * 1536);
    const float4* A4 = (const float4*)a_score;
    float aq = 0.f, ak = 0.f;
#pragma unroll
    for (int k = 0; k < 2; ++k) {
        float4 f = R4[lane + 64 * k];
        float4 a = A4[lane + 64 * k];
        aq += f.x * a.x + f.y * a.y + f.z * a.z + f.w * a.w;
        float4 g = R4[128 + lane + 64 * k];
        float4 a2 = A4[128 + lane + 64 * k];
        ak += g.x * a2.x + g.y * a2.y + g.z * a2.z + g.w * a2.w;
    }
#pragma unroll
    for (int off = 32; off; off >>= 1) { aq += __shfl_xor(aq, off); ak += __shfl_xor(ak, off); }
    if (lane == 0) { wsf[WQ_F + e] = aq; wsf[WK_F + e] = ak; }
}

__global__ void k_prep_cqk(const float* __restrict__ b_w, const float* __restrict__ a_score,
                           const float* __restrict__ b_score, float* wsf) {
    __shared__ float s1[512], s2[512];
    int t = threadIdx.x;
    s1[t] = b_w[t] * a_score[t];
    s2[t] = b_w[512 + t] * a_score[512 + t];
    __syncthreads();
    for (int off = 256; off > 0; off >>= 1) {
        if (t < off) { s1[t] += s1[t + off]; s2[t] += s2[t + off]; }
        __syncthreads();
    }
    if (t == 0) { wsf[CQB_F] = s1[0] + b_score[0]; wsf[CK_F] = s2[0]; }
}

// Wt[d][e] = sum_h W_w[e,1024+h] * W_out[h,d]  (bf16 out, transposed W_comb)
// also bcomb[d] = sum_h b_w[1024+h] * W_out[h,d]  (computed by e0==0 blocks)
// 256 blocks x 256 thr; 32x32 tile; BK=32; 2x2 micro-tile.
__global__ __launch_bounds__(256) void k_wt(const float* __restrict__ W_w,
                                            const float* __restrict__ W_out,
                                            const float* __restrict__ b_w,
                                            char* wsb, float* wsf) {
    __shared__ float As[32][34];   // [h][d]  +2 pad (keeps float2 8B-aligned)
    __shared__ float Bs[32][34];   // [h][e]
    const int t = threadIdx.x;
    const int d0 = (blockIdx.x & 15) * 32;
    const int e0 = (blockIdx.x >> 4) * 32;
    const int ty = t >> 4, tx = t & 15;
    const int hl = t >> 5, c = t & 31;     // loader coords: 8 rows/pass x 32 cols
    float a00 = 0.f, a01 = 0.f, a10 = 0.f, a11 = 0.f;
    float bc = 0.f;
    for (int k0 = 0; k0 < 512; k0 += 32) {
#pragma unroll
        for (int r = 0; r < 4; ++r) {
            int h = hl + 8 * r;
            As[h][c] = W_out[(size_t)(k0 + h) * 512 + d0 + c];
            Bs[c][h] = W_w[(size_t)(e0 + h) * 1536 + 1024 + k0 + c];
        }
        __syncthreads();
        if (e0 == 0 && t < 32) {
#pragma unroll
            for (int kk = 0; kk < 32; ++kk)
                bc = fmaf(b_w[1024 + k0 + kk], As[kk][t], bc);
        }
#pragma unroll
        for (int kk = 0; kk < 32; ++kk) {
            float2 a2 = *(const float2*)&As[kk][ty * 2];
            float2 b2 = *(const float2*)&Bs[kk][tx * 2];
            a00 = fmaf(a2.x, b2.x, a00);
            a01 = fmaf(a2.x, b2.y, a01);
            a10 = fmaf(a2.y, b2.x, a10);
            a11 = fmaf(a2.y, b2.y, a11);
        }
        __syncthreads();
    }
    unsigned short* Wt = (unsigned short*)(wsb + WT_OFF);
    const int d = d0 + ty * 2, e = e0 + tx * 2;
    Wt[(size_t)d * 512 + e]           = bf16u(a00);
    Wt[(size_t)d * 512 + e + 1]       = bf16u(a01);
    Wt[(size_t)(d + 1) * 512 + e]     = bf16u(a10);
    Wt[(size_t)(d + 1) * 512 + e + 1] = bf16u(a11);
    if (e0 == 0 && t < 32) wsf[BCOMB_F + d0 + t] = bc;
}

// sq'[n], sk'[n]
__global__ void k_sqsk(const float* __restrict__ feat, float* wsf) {
    int wave = threadIdx.x >> 6, lane = threadIdx.x & 63;
    int n = blockIdx.x * 4 + wave;
    const float4* F4 = (const float4*)(feat + (size_t)n * 512);
    const float4* WQ4 = (const float4*)(wsf + WQ_F);
    const float4* WK4 = (const float4*)(wsf + WK_F);
    float aq = 0.f, ak = 0.f;
#pragma unroll
    for (int k = 0; k < 2; ++k) {
        float4 f = F4[lane + 64 * k];
        float4 q = WQ4[lane + 64 * k];
        float4 kk = WK4[lane + 64 * k];
        aq += f.x * q.x + f.y * q.y + f.z * q.z + f.w * q.w;
        ak += f.x * kk.x + f.y * kk.y + f.z * kk.z + f.w * kk.w;
    }
#pragma unroll
    for (int off = 32; off; off >>= 1) { aq += __shfl_xor(aq, off); ak += __shfl_xor(ak, off); }
    if (lane == 0) {
        wsf[SQP_F + n] = aq + wsf[CQB_F];
        wsf[SKP_F + n] = ak + wsf[CK_F];
    }
}

// per-row max & sum of z = mask * lrelu(sq'+sk')
__global__ void k_rowstats(const float* __restrict__ mask, float* wsf) {
    int wave = threadIdx.x >> 6, lane = threadIdx.x & 63;
    int n = blockIdx.x * 4 + wave;
    int b = n >> 11, i = n & 2047;
    const float4* M4 = (const float4*)(mask + ((size_t)b * C_ + i) * C_);
    const float4* SK4 = (const float4*)(wsf + SKP_F + (size_t)b * C_);
    const float sq = wsf[SQP_F + n];
    float z[32];
    float m = -1e30f;
#pragma unroll
    for (int k = 0; k < 8; ++k) {
        float4 mk = M4[k * 64 + lane];
        float4 sk = SK4[k * 64 + lane];
        float t0;
        t0 = sq + sk.x; t0 = fmaxf(t0, t0 * NEG_SLOPE) * mk.x; z[k * 4 + 0] = t0;
        t0 = sq + sk.y; t0 = fmaxf(t0, t0 * NEG_SLOPE) * mk.y; z[k * 4 + 1] = t0;
        t0 = sq + sk.z; t0 = fmaxf(t0, t0 * NEG_SLOPE) * mk.z; z[k * 4 + 2] = t0;
        t0 = sq + sk.w; t0 = fmaxf(t0, t0 * NEG_SLOPE) * mk.w; z[k * 4 + 3] = t0;
    }
#pragma unroll
    for (int q = 0; q < 32; ++q) m = fmaxf(m, z[q]);
#pragma unroll
    for (int off = 32; off; off >>= 1) m = fmaxf(m, __shfl_xor(m, off));
    float s = 0.f;
#pragma unroll
    for (int q = 0; q < 32; ++q) s += __expf(z[q] - m);
#pragma unroll
    for (int off = 32; off; off >>= 1) s += __shfl_xor(s, off);
    if (lane == 0) { wsf[RMAX_F + n] = m; wsf[RSUM_F + n] = s; }
}

// Ut[b,d,j] = sum_e Wt[d,e] * F[b,j,e]   (bf16 MFMA; full K=512 staged in LDS)
__global__ __launch_bounds__(512) void k_ut(const float* __restrict__ F, char* __restrict__ wsb) {
    __shared__ unsigned short Fb[64][520];   // [j][e] +8 pad
    const int t = threadIdx.x;
    const int bid = blockIdx.x;
    const int b = bid & 7, j0 = (bid >> 3) * 64;
    const unsigned short* Wt = (const unsigned short*)(wsb + WT_OFF);
    unsigned short* Ut = (unsigned short*)(wsb + UT_OFF) + (size_t)b * 512 * 2048;
    const float* Ft = F + ((size_t)(b * C_ + j0)) * 512;   // 64x512 tile, contiguous
#pragma unroll
    for (int q = 0; q < 16; ++q) {
        float4 v = *(const float4*)(Ft + (size_t)q * 2048 + t * 4);
        int jr = 4 * q + (t >> 7);
        int e = (t & 127) * 4;
        unsigned int lo = (unsigned int)bf16u(v.x) | ((unsigned int)bf16u(v.y) << 16);
        unsigned int hi = (unsigned int)bf16u(v.z) | ((unsigned int)bf16u(v.w) << 16);
        *(uint2*)&Fb[jr][e] = make_uint2(lo, hi);
    }
    __syncthreads();
    const int l = t & 63, lr = l & 15, lg = l >> 4;
    const int d0 = (t >> 6) * 64;
    f32x4 acc[4][4];
#pragma unroll
    for (int m = 0; m < 4; ++m)
#pragma unroll
        for (int n = 0; n < 4; ++n) acc[m][n] = (f32x4){0.f, 0.f, 0.f, 0.f};
#pragma unroll
    for (int ks = 0; ks < 16; ++ks) {
        bf16x8 af[4], bv[4];
#pragma unroll
        for (int m = 0; m < 4; ++m)
            af[m] = *(const bf16x8*)(Wt + (size_t)(d0 + 16 * m + lr) * 512 + ks * 32 + 8 * lg);
#pragma unroll
        for (int n = 0; n < 4; ++n)
            bv[n] = *(const bf16x8*)&Fb[16 * n + lr][ks * 32 + 8 * lg];
#pragma unroll
        for (int m = 0; m < 4; ++m)
#pragma unroll
            for (int n = 0; n < 4; ++n)
                acc[m][n] = __builtin_amdgcn_mfma_f32_16x16x32_bf16(af[m], bv[n], acc[m][n], 0, 0, 0);
    }
#pragma unroll
    for (int m = 0; m < 4; ++m)
#pragma unroll
        for (int n = 0; n < 4; ++n)
#pragma unroll
            for (int r = 0; r < 4; ++r) {
                int d = d0 + 16 * m + lg * 4 + r;
                int j = j0 + 16 * n + lr;
                Ut[(size_t)d * 2048 + j] = bf16u(acc[m][n][r]);
            }
}

// out[b,i,d] = rinv_i * sum_j exp(z_ij - m_i) * Ut[d,j]  + b_comb[d] + b_out[d]
__global__ __launch_bounds__(512) void k_attn(const float* __restrict__ mask,
                                              const float* __restrict__ b_out,
                                              char* __restrict__ wsb,
                                              float* __restrict__ out) {
    __shared__ unsigned short P[2][64][72];   // double-buffered P tile, +8 pad
    __shared__ float sqs[64], ms[64], rinv[64], bcbo[512];
    const int t = threadIdx.x;
    const int bid = blockIdx.x;
    const int b = bid & 7, i0 = (bid >> 3) * 64;
    const float* wsf = (const float*)(wsb + FP_OFF);
    const unsigned short* Ut = (const unsigned short*)(wsb + UT_OFF) + (size_t)b * 512 * 2048;
    if (t < 64) {
        int n = b * C_ + i0 + t;
        sqs[t] = wsf[SQP_F + n];
        ms[t] = wsf[RMAX_F + n];
        rinv[t] = 1.0f / wsf[RSUM_F + n];
    }
    bcbo[t] = wsf[BCOMB_F + t] + b_out[t];
    __syncthreads();
    const int ip = t >> 3, jc = t & 7;           // P-compute: row ip, 8 cols at jc*8
    const int l = t & 63, lr = l & 15, lg = l >> 4;
    const int dw = (t >> 6) * 64;                // wave's 64-col slice of d
    const float* mrow = mask + ((size_t)(b * C_ + i0 + ip)) * C_;
    const float* skb = wsf + SKP_F + b * C_;
    const float sqv = sqs[ip], mv = ms[ip];
    f32x4 acc[4][4];
#pragma unroll
    for (int m = 0; m < 4; ++m)
#pragma unroll
        for (int n = 0; n < 4; ++n) acc[m][n] = (f32x4){0.f, 0.f, 0.f, 0.f};

    auto computeP = [&](int kt, int buf) {
        const int j = kt * 64 + jc * 8;
        float4 mk0 = *(const float4*)(mrow + j);
        float4 mk1 = *(const float4*)(mrow + j + 4);
        float4 sk0 = *(const float4*)(skb + j);
        float4 sk1 = *(const float4*)(skb + j + 4);
        bf16x8 v;
        float z;
        z = sqv + sk0.x; z = fmaxf(z, z * NEG_SLOPE) * mk0.x; v[0] = (short)bf16u(__expf(z - mv));
        z = sqv + sk0.y; z = fmaxf(z, z * NEG_SLOPE) * mk0.y; v[1] = (short)bf16u(__expf(z - mv));
        z = sqv + sk0.z; z = fmaxf(z, z * NEG_SLOPE) * mk0.z; v[2] = (short)bf16u(__expf(z - mv));
        z = sqv + sk0.w; z = fmaxf(z, z * NEG_SLOPE) * mk0.w; v[3] = (short)bf16u(__expf(z - mv));
        z = sqv + sk1.x; z = fmaxf(z, z * NEG_SLOPE) * mk1.x; v[4] = (short)bf16u(__expf(z - mv));
        z = sqv + sk1.y; z = fmaxf(z, z * NEG_SLOPE) * mk1.y; v[5] = (short)bf16u(__expf(z - mv));
        z = sqv + sk1.z; z = fmaxf(z, z * NEG_SLOPE) * mk1.z; v[6] = (short)bf16u(__expf(z - mv));
        z = sqv + sk1.w; z = fmaxf(z, z * NEG_SLOPE) * mk1.w; v[7] = (short)bf16u(__expf(z - mv));
        *(bf16x8*)&P[buf][ip][jc * 8] = v;
    };

    computeP(0, 0);
    __syncthreads();
    for (int kt = 0; kt < 32; ++kt) {
        const int cur = kt & 1;
        if (kt + 1 < 32) computeP(kt + 1, cur ^ 1);
#pragma unroll
        for (int ks = 0; ks < 2; ++ks) {
            bf16x8 af[4], bv[4];
#pragma unroll
            for (int m = 0; m < 4; ++m)
                af[m] = *(const bf16x8*)&P[cur][16 * m + lr][ks * 32 + 8 * lg];
#pragma unroll
            for (int n = 0; n < 4; ++n)
                bv[n] = *(const bf16x8*)(Ut + (size_t)(dw + 16 * n + lr) * 2048 + kt * 64 + ks * 32 + 8 * lg);
#pragma unroll
            for (int m = 0; m < 4; ++m)
#pragma unroll
                for (int n = 0; n < 4; ++n)
                    acc[m][n] = __builtin_amdgcn_mfma_f32_16x16x32_bf16(af[m], bv[n], acc[m][n], 0, 0, 0);
        }
        __syncthreads();
    }
#pragma unroll
    for (int m = 0; m < 4; ++m) {
#pragma unroll
        for (int r = 0; r < 4; ++r) {
            const int irow = 16 * m + lg * 4 + r;
            const float rv = rinv[irow];
            float* orow = out + ((size_t)(b * C_ + i0 + irow)) * DIM_ + dw;
#pragma unroll
            for (int n = 0; n < 4; ++n)
                orow[16 * n + lr] = acc[m][n][r] * rv + bcbo[dw + 16 * n + lr];
        }
    }
}

extern "C" void kernel_launch(void* const* d_in, const int* in_sizes, int n_in,
                              void* d_out, int out_size, void* d_ws, size_t ws_size,
                              hipStream_t stream) {
    const float* features = (const float*)d_in[0];
    const float* mask     = (const float*)d_in[1];
    const float* W_w      = (const float*)d_in[2];
    const float* b_w      = (const float*)d_in[3];
    const float* a_score  = (const float*)d_in[4];
    const float* b_score  = (const float*)d_in[5];
    const float* W_out    = (const float*)d_in[6];
    const float* b_out    = (const float*)d_in[7];
    float* out = (float*)d_out;
    char* wsb  = (char*)d_ws;
    float* wsf = (float*)(wsb + FP_OFF);

    k_prep_wqk<<<128, 256, 0, stream>>>(W_w, a_score, wsf);
    k_prep_cqk<<<1, 512, 0, stream>>>(b_w, a_score, b_score, wsf);
    k_wt<<<256, 256, 0, stream>>>(W_w, W_out, b_w, wsb, wsf);
    k_sqsk<<<4096, 256, 0, stream>>>(features, wsf);
    k_rowstats<<<4096, 256, 0, stream>>>(mask, wsf);
    k_ut<<<256, 512, 0, stream>>>(features, wsb);
    k_attn<<<256, 512, 0, stream>>>(mask, b_out, wsb, out);
}

// Round 5
// 175.995 us; speedup vs baseline: 4.4084x; 1.0094x over previous
//
#include <hip/hip_runtime.h>
#include <hip/hip_bf16.h>

#define B_ 8
#define C_ 2048
#define DIM_ 512
#define NEG_SLOPE 0.01f

typedef short bf16x8 __attribute__((ext_vector_type(8)));
typedef float f32x4 __attribute__((ext_vector_type(4)));

// ---- workspace byte offsets
#define WT_OFF   0                        // bf16 Wt[512][512] (W_comb^T)
#define UT_OFF   524288                   // bf16 Ut[8*512][2048]  (U^T per batch)
#define FP_OFF   (524288 + 16777216)      // fp32 region
// ---- float offsets inside fp32 region
#define BCOMB_F  0
#define WQ_F     512
#define WK_F     1024
#define CQB_F    1536
#define CK_F     1537
#define SQP_F    2048
#define SKP_F    18432

static __device__ __forceinline__ unsigned short bf16u(float x) {
    union { __hip_bfloat16 h; unsigned short u; } c;
    c.h = __float2bfloat16(x);
    return c.u;
}

// wq_vec[e] = sum_h W_w[e,h]*a[h]; wk_vec[e] = sum_h W_w[e,512+h]*a[512+h]
__global__ void k_prep_wqk(const float* __restrict__ W_w, const float* __restrict__ a_score, float* wsf) {
    int wave = threadIdx.x >> 6, lane = threadIdx.x & 63;
    int e = blockIdx.x * 4 + wave;
    const float4* R4 = (const float4*)(W_w + (size_t)e * 1536);
    const float4* A4 = (const float4*)a_score;
    float aq = 0.f, ak = 0.f;
#pragma unroll
    for (int k = 0; k < 2; ++k) {
        float4 f = R4[lane + 64 * k];
        float4 a = A4[lane + 64 * k];
        aq += f.x * a.x + f.y * a.y + f.z * a.z + f.w * a.w;
        float4 g = R4[128 + lane + 64 * k];
        float4 a2 = A4[128 + lane + 64 * k];
        ak += g.x * a2.x + g.y * a2.y + g.z * a2.z + g.w * a2.w;
    }
#pragma unroll
    for (int off = 32; off; off >>= 1) { aq += __shfl_xor(aq, off); ak += __shfl_xor(ak, off); }
    if (lane == 0) { wsf[WQ_F + e] = aq; wsf[WK_F + e] = ak; }
}

__global__ void k_prep_cqk(const float* __restrict__ b_w, const float* __restrict__ a_score,
                           const float* __restrict__ b_score, float* wsf) {
    __shared__ float s1[512], s2[512];
    int t = threadIdx.x;
    s1[t] = b_w[t] * a_score[t];
    s2[t] = b_w[512 + t] * a_score[512 + t];
    __syncthreads();
    for (int off = 256; off > 0; off >>= 1) {
        if (t < off) { s1[t] += s1[t + off]; s2[t] += s2[t + off]; }
        __syncthreads();
    }
    if (t == 0) { wsf[CQB_F] = s1[0] + b_score[0]; wsf[CK_F] = s2[0]; }
}

// Wt[d][e] = sum_h W_w[e,1024+h]*W_out[h,d]; bcomb[d] = sum_h b_w[1024+h]*W_out[h,d]
__global__ __launch_bounds__(256) void k_wt(const float* __restrict__ W_w,
                                            const float* __restrict__ W_out,
                                            const float* __restrict__ b_w,
                                            char* wsb, float* wsf) {
    __shared__ float As[32][34];
    __shared__ float Bs[32][34];
    const int t = threadIdx.x;
    const int d0 = (blockIdx.x & 15) * 32;
    const int e0 = (blockIdx.x >> 4) * 32;
    const int ty = t >> 4, tx = t & 15;
    const int hl = t >> 5, c = t & 31;
    float a00 = 0.f, a01 = 0.f, a10 = 0.f, a11 = 0.f;
    float bc = 0.f;
    for (int k0 = 0; k0 < 512; k0 += 32) {
#pragma unroll
        for (int r = 0; r < 4; ++r) {
            int h = hl + 8 * r;
            As[h][c] = W_out[(size_t)(k0 + h) * 512 + d0 + c];
            Bs[c][h] = W_w[(size_t)(e0 + h) * 1536 + 1024 + k0 + c];
        }
        __syncthreads();
        if (e0 == 0 && t < 32) {
#pragma unroll
            for (int kk = 0; kk < 32; ++kk)
                bc = fmaf(b_w[1024 + k0 + kk], As[kk][t], bc);
        }
#pragma unroll
        for (int kk = 0; kk < 32; ++kk) {
            float2 a2 = *(const float2*)&As[kk][ty * 2];
            float2 b2 = *(const float2*)&Bs[kk][tx * 2];
            a00 = fmaf(a2.x, b2.x, a00);
            a01 = fmaf(a2.x, b2.y, a01);
            a10 = fmaf(a2.y, b2.x, a10);
            a11 = fmaf(a2.y, b2.y, a11);
        }
        __syncthreads();
    }
    unsigned short* Wt = (unsigned short*)(wsb + WT_OFF);
    const int d = d0 + ty * 2, e = e0 + tx * 2;
    Wt[(size_t)d * 512 + e]           = bf16u(a00);
    Wt[(size_t)d * 512 + e + 1]       = bf16u(a01);
    Wt[(size_t)(d + 1) * 512 + e]     = bf16u(a10);
    Wt[(size_t)(d + 1) * 512 + e + 1] = bf16u(a11);
    if (e0 == 0 && t < 32) wsf[BCOMB_F + d0 + t] = bc;
}

// sq'[n], sk'[n]
__global__ void k_sqsk(const float* __restrict__ feat, float* wsf) {
    int wave = threadIdx.x >> 6, lane = threadIdx.x & 63;
    int n = blockIdx.x * 4 + wave;
    const float4* F4 = (const float4*)(feat + (size_t)n * 512);
    const float4* WQ4 = (const float4*)(wsf + WQ_F);
    const float4* WK4 = (const float4*)(wsf + WK_F);
    float aq = 0.f, ak = 0.f;
#pragma unroll
    for (int k = 0; k < 2; ++k) {
        float4 f = F4[lane + 64 * k];
        float4 q = WQ4[lane + 64 * k];
        float4 kk = WK4[lane + 64 * k];
        aq += f.x * q.x + f.y * q.y + f.z * q.z + f.w * q.w;
        ak += f.x * kk.x + f.y * kk.y + f.z * kk.z + f.w * kk.w;
    }
#pragma unroll
    for (int off = 32; off; off >>= 1) { aq += __shfl_xor(aq, off); ak += __shfl_xor(ak, off); }
    if (lane == 0) {
        wsf[SQP_F + n] = aq + wsf[CQB_F];
        wsf[SKP_F + n] = ak + wsf[CK_F];
    }
}

// Ut[b,d,j] = sum_e Wt[d,e] * F[b,j,e]   (512 blocks: j-tile 32, 4 waves x 128 d)
__global__ __launch_bounds__(256) void k_ut(const float* __restrict__ F, char* __restrict__ wsb) {
    __shared__ unsigned short Fb[32][520];
    const int t = threadIdx.x;
    const int bid = blockIdx.x;
    const int b = bid & 7, j0 = (bid >> 3) * 32;
    const unsigned short* Wt = (const unsigned short*)(wsb + WT_OFF);
    unsigned short* Ut = (unsigned short*)(wsb + UT_OFF) + (size_t)b * 512 * 2048;
    const float* Ft = F + ((size_t)(b * C_ + j0)) * 512;
#pragma unroll
    for (int q = 0; q < 16; ++q) {                      // FIX: 16 passes covers all 32 rows
        float4 v = *(const float4*)(Ft + (size_t)q * 1024 + t * 4);
        int jr = 2 * q + (t >> 7);
        int e = (t & 127) * 4;
        unsigned int lo = (unsigned int)bf16u(v.x) | ((unsigned int)bf16u(v.y) << 16);
        unsigned int hi = (unsigned int)bf16u(v.z) | ((unsigned int)bf16u(v.w) << 16);
        *(uint2*)&Fb[jr][e] = make_uint2(lo, hi);
    }
    __syncthreads();
    const int l = t & 63, lr = l & 15, lg = l >> 4;
    const int d0 = (t >> 6) * 128;
    f32x4 acc[8][2];
#pragma unroll
    for (int m = 0; m < 8; ++m)
#pragma unroll
        for (int n = 0; n < 2; ++n) acc[m][n] = (f32x4){0.f, 0.f, 0.f, 0.f};
#pragma unroll
    for (int ks = 0; ks < 16; ++ks) {
        bf16x8 af[8], bv[2];
#pragma unroll
        for (int m = 0; m < 8; ++m)
            af[m] = *(const bf16x8*)(Wt + (size_t)(d0 + 16 * m + lr) * 512 + ks * 32 + 8 * lg);
#pragma unroll
        for (int n = 0; n < 2; ++n)
            bv[n] = *(const bf16x8*)&Fb[16 * n + lr][ks * 32 + 8 * lg];
#pragma unroll
        for (int m = 0; m < 8; ++m)
#pragma unroll
            for (int n = 0; n < 2; ++n)
                acc[m][n] = __builtin_amdgcn_mfma_f32_16x16x32_bf16(af[m], bv[n], acc[m][n], 0, 0, 0);
    }
#pragma unroll
    for (int m = 0; m < 8; ++m)
#pragma unroll
        for (int n = 0; n < 2; ++n)
#pragma unroll
            for (int r = 0; r < 4; ++r) {
                int d = d0 + 16 * m + lg * 4 + r;
                int j = j0 + 16 * n + lr;
                Ut[(size_t)d * 2048 + j] = bf16u(acc[m][n][r]);
            }
}

// fused: out[b,i,d] = (1/sum_j p_ij) * sum_j p_ij * Ut[d,j] + bcomb[d] + b_out[d]
//        p_ij = exp(mask_ij * lrelu(sq_i + sk_j))        (no max subtraction: |z| <~ 2)
#define ISSUE(S, KT) { \
    mk##S##a = __builtin_nontemporal_load((const f32x4*)(mrowp + (KT) * 64)); \
    mk##S##b = __builtin_nontemporal_load((const f32x4*)(mrowp + (KT) * 64 + 4)); }

#define PC1(ZS, MKC, VI) { \
    float z = sqv + (ZS); z = fmaxf(z, z * NEG_SLOPE) * (MKC); \
    float p = __expf(z); psum += p; vv[VI] = (short)bf16u(p); }

#define PCOMP(S, BUF, KT) { \
    float4 ska = *(const float4*)&sk_lds[(KT) * 64 + jc * 8]; \
    float4 skc = *(const float4*)&sk_lds[(KT) * 64 + jc * 8 + 4]; \
    bf16x8 vv; \
    PC1(ska.x, mk##S##a.x, 0) PC1(ska.y, mk##S##a.y, 1) \
    PC1(ska.z, mk##S##a.z, 2) PC1(ska.w, mk##S##a.w, 3) \
    PC1(skc.x, mk##S##b.x, 4) PC1(skc.y, mk##S##b.y, 5) \
    PC1(skc.z, mk##S##b.z, 6) PC1(skc.w, mk##S##b.w, 7) \
    *(bf16x8*)&P[BUF][ip][jc * 8] = vv; }

#define MFTILE(BUF, KT) { \
    bf16x8 bvA[4], bvB[4]; \
    _Pragma("unroll") \
    for (int n = 0; n < 4; ++n) { \
        const bf16x8* up = (const bf16x8*)(Ut + (size_t)(dw + 16 * n + lr) * 2048 + (KT) * 64 + 8 * lg); \
        bvA[n] = up[0]; bvB[n] = up[4];   /* FIX: ks=1 slice is +32 elems = up[4] */ \
    } \
    _Pragma("unroll") \
    for (int m = 0; m < 4; ++m) { \
        bf16x8 af = *(const bf16x8*)&P[BUF][16 * m + lr][8 * lg]; \
        _Pragma("unroll") \
        for (int n = 0; n < 4; ++n) \
            acc[m][n] = __builtin_amdgcn_mfma_f32_16x16x32_bf16(af, bvA[n], acc[m][n], 0, 0, 0); \
    } \
    _Pragma("unroll") \
    for (int m = 0; m < 4; ++m) { \
        bf16x8 af = *(const bf16x8*)&P[BUF][16 * m + lr][32 + 8 * lg]; \
        _Pragma("unroll") \
        for (int n = 0; n < 4; ++n) \
            acc[m][n] = __builtin_amdgcn_mfma_f32_16x16x32_bf16(af, bvB[n], acc[m][n], 0, 0, 0); \
    } }

__global__ __launch_bounds__(512) void k_attn(const float* __restrict__ mask,
                                              const float* __restrict__ b_out,
                                              char* __restrict__ wsb,
                                              float* __restrict__ out) {
    __shared__ unsigned short P[2][64][72];
    __shared__ float sk_lds[2048];
    __shared__ float sqs[64], rinvs[64], bcbo[512];
    __shared__ float psums[64][8];
    const int t = threadIdx.x;
    const int bid = blockIdx.x;
    const int b = bid & 7, i0 = (bid >> 3) * 64;
    const float* wsf = (const float*)(wsb + FP_OFF);
    const unsigned short* Ut = (const unsigned short*)(wsb + UT_OFF) + (size_t)b * 512 * 2048;
    const int ip = t >> 3, jc = t & 7;
    const int l = t & 63, lr = l & 15, lg = l >> 4;
    const int dw = (t >> 6) * 64;
    const float* mrowp = mask + ((size_t)(b * C_ + i0 + ip)) * C_ + jc * 8;

    f32x4 mk0a, mk0b, mk1a, mk1b, mk2a, mk2b, mk3a, mk3b;
    ISSUE(0, 0) ISSUE(1, 1) ISSUE(2, 2) ISSUE(3, 3)

    {   // stage sk row, sq, bias
        const float* skb = wsf + SKP_F + b * C_;
        *(float4*)&sk_lds[t * 4] = *(const float4*)(skb + t * 4);
        if (t < 64) sqs[t] = wsf[SQP_F + b * C_ + i0 + t];
        bcbo[t] = wsf[BCOMB_F + t] + b_out[t];
    }
    __syncthreads();
    const float sqv = sqs[ip];
    float psum = 0.f;
    f32x4 acc[4][4];
#pragma unroll
    for (int m = 0; m < 4; ++m)
#pragma unroll
        for (int n = 0; n < 4; ++n) acc[m][n] = (f32x4){0.f, 0.f, 0.f, 0.f};

    PCOMP(0, 0, 0)
    __syncthreads();

    for (int o = 0; o < 8; ++o) {
        const int kt = o * 4;
        if (kt + 4 < 32) ISSUE(0, kt + 4)
        PCOMP(1, 1, kt + 1)
        MFTILE(0, kt)
        __syncthreads();
        if (kt + 5 < 32) ISSUE(1, kt + 5)
        PCOMP(2, 0, kt + 2)
        MFTILE(1, kt + 1)
        __syncthreads();
        if (kt + 6 < 32) ISSUE(2, kt + 6)
        PCOMP(3, 1, kt + 3)
        MFTILE(0, kt + 2)
        __syncthreads();
        if (kt + 7 < 32) ISSUE(3, kt + 7)
        if (kt + 4 < 32) PCOMP(0, 0, kt + 4)
        MFTILE(1, kt + 3)
        __syncthreads();
    }

    psums[ip][jc] = psum;
    __syncthreads();
    if (t < 64) {
        float4 pa = *(const float4*)&psums[t][0];
        float4 pb = *(const float4*)&psums[t][4];
        rinvs[t] = 1.0f / (pa.x + pa.y + pa.z + pa.w + pb.x + pb.y + pb.z + pb.w);
    }
    __syncthreads();
#pragma unroll
    for (int m = 0; m < 4; ++m) {
#pragma unroll
        for (int r = 0; r < 4; ++r) {
            const int irow = 16 * m + lg * 4 + r;
            const float rv = rinvs[irow];
            float* orow = out + ((size_t)(b * C_ + i0 + irow)) * DIM_ + dw;
#pragma unroll
            for (int n = 0; n < 4; ++n)
                orow[16 * n + lr] = acc[m][n][r] * rv + bcbo[dw + 16 * n + lr];
        }
    }
}

extern "C" void kernel_launch(void* const* d_in, const int* in_sizes, int n_in,
                              void* d_out, int out_size, void* d_ws, size_t ws_size,
                              hipStream_t stream) {
    const float* features = (const float*)d_in[0];
    const float* mask     = (const float*)d_in[1];
    const float* W_w      = (const float*)d_in[2];
    const float* b_w      = (const float*)d_in[3];
    const float* a_score  = (const float*)d_in[4];
    const float* b_score  = (const float*)d_in[5];
    const float* W_out    = (const float*)d_in[6];
    const float* b_out    = (const float*)d_in[7];
    float* out = (float*)d_out;
    char* wsb  = (char*)d_ws;
    float* wsf = (float*)(wsb + FP_OFF);

    k_prep_wqk<<<128, 256, 0, stream>>>(W_w, a_score, wsf);
    k_prep_cqk<<<1, 512, 0, stream>>>(b_w, a_score, b_score, wsf);
    k_wt<<<256, 256, 0, stream>>>(W_w, W_out, b_w, wsb, wsf);
    k_sqsk<<<4096, 256, 0, stream>>>(features, wsf);
    k_ut<<<512, 256, 0, stream>>>(features, wsb);
    k_attn<<<256, 512, 0, stream>>>(mask, b_out, wsb, out);
}